// Round 6
// baseline (1072.871 us; speedup 1.0000x reference)
//
#include <hip/hip_runtime.h>
#include <hip/hip_bf16.h>
#include <math.h>

// ---------------------------------------------------------------------------
// SwinDiT block, f32 I/O + bf16 MFMA internals, MI355X.
// B=1, D=16,H=64,W=64 -> L=65536 tokens, C=512. Windows 4x8x8=256 tokens,
// 256 windows, 8 heads, d=64. HIDDEN=2048.
// ---------------------------------------------------------------------------

typedef __attribute__((ext_vector_type(8))) short short8;   // 8 x bf16
typedef __attribute__((ext_vector_type(4))) short bs4;      // 4 x bf16
typedef __attribute__((ext_vector_type(4))) float f32x4;

typedef const __attribute__((address_space(1))) unsigned int gu32;
typedef __attribute__((address_space(3))) unsigned int lu32;

__device__ __forceinline__ float bf2f(short s) {
  unsigned int u = ((unsigned int)(unsigned short)s) << 16;
  float f;
  __builtin_memcpy(&f, &u, 4);
  return f;
}
__device__ __forceinline__ short f2bf(float f) {
  unsigned int u;
  __builtin_memcpy(&u, &f, 4);
  u += 0x7FFFu + ((u >> 16) & 1u);   // RNE
  return (short)(u >> 16);
}
__device__ __forceinline__ short f2bf_trunc(float f) {
  unsigned int u;
  __builtin_memcpy(&u, &f, 4);
  return (short)(u >> 16);
}

// window-layout row p -> original token index s (roll(-2,-4,-4) + window partition)
__device__ __forceinline__ int win_to_src(int p) {
  int wi = p >> 8, t = p & 255;
  int sd = (((wi >> 6) << 2) + (t >> 6) + 2) & 15;
  int sh = ((((wi >> 3) & 7) << 3) + ((t >> 3) & 7) + 4) & 63;
  int sw = (((wi & 7) << 3) + (t & 7) + 4) & 63;
  return (sd << 12) | (sh << 6) | sw;
}

// ---------------------------------------------------------------------------
// K0: mod = silu(t_emb) @ ada_w + ada_b   -> f32 [3072]
// ---------------------------------------------------------------------------
__global__ __launch_bounds__(256) void mod_kernel(
    const float* __restrict__ t_emb, const float* __restrict__ ada_w,
    const float* __restrict__ ada_b, float* __restrict__ mod) {
  __shared__ float sl[512];
  int tid = threadIdx.x;
  for (int r = 0; r < 2; ++r) {
    float x = t_emb[r * 256 + tid];
    sl[r * 256 + tid] = x / (1.f + expf(-x));
  }
  __syncthreads();
  int col = blockIdx.x * 256 + tid;
  float acc = ada_b[col];
  for (int k = 0; k < 512; ++k)
    acc += sl[k] * ada_w[(size_t)k * 3072 + col];
  mod[col] = acc;
}

// ---------------------------------------------------------------------------
// K1: rel-pos bias expand, TRANSPOSED bf16: biasT[head][key j][q i]
// ---------------------------------------------------------------------------
__global__ __launch_bounds__(256) void bias_kernel(
    const float* __restrict__ rel_table, short* __restrict__ biasT) {
  int head = blockIdx.x >> 8;
  int j = blockIdx.x & 255;   // key
  int i = threadIdx.x;        // q
  int di = i >> 6, hi = (i >> 3) & 7, wi = i & 7;
  int dj = j >> 6, hj = (j >> 3) & 7, wj = j & 7;
  int idx = (di - dj + 3) * 225 + (hi - hj + 7) * 15 + (wi - wj + 7);
  biasT[(size_t)blockIdx.x * 256 + i] = f2bf(rel_table[idx * 8 + head]);
}

// ---------------------------------------------------------------------------
// K2: transpose + convert: f32 [K,N] -> bf16 [N,K]
// ---------------------------------------------------------------------------
__global__ __launch_bounds__(256) void transpose_kernel(
    const float* __restrict__ in, short* __restrict__ out, int K, int N) {
  __shared__ short t[32][33];
  int n0 = blockIdx.x * 32, k0 = blockIdx.y * 32;
  int tx = threadIdx.x & 31, ty = threadIdx.x >> 5;
#pragma unroll
  for (int r = 0; r < 4; ++r)
    t[ty + r * 8][tx] = f2bf(in[(size_t)(k0 + ty + r * 8) * N + n0 + tx]);
  __syncthreads();
#pragma unroll
  for (int r = 0; r < 4; ++r)
    out[(size_t)(n0 + ty + r * 8) * K + k0 + tx] = t[tx][ty + r * 8];
}

// ---------------------------------------------------------------------------
// K3: LayerNorm + adaLN modulate. f32 in -> bf16 out.
// GATHER=1: out row p <- src row win_to_src(p)
// ---------------------------------------------------------------------------
template <int GATHER>
__global__ __launch_bounds__(256) void ln_kernel(
    const float* __restrict__ xin, short* __restrict__ xout,
    const float* __restrict__ shv, const float* __restrict__ scv) {
  int wave = threadIdx.x >> 6, lane = threadIdx.x & 63;
  int p = blockIdx.x * 4 + wave;
  int s = GATHER ? win_to_src(p) : p;
  const f32x4* px = (const f32x4*)(xin + (size_t)s * 512 + lane * 8);
  f32x4 a = px[0], b = px[1];
  float xs[8];
#pragma unroll
  for (int j = 0; j < 4; ++j) { xs[j] = a[j]; xs[4 + j] = b[j]; }
  float sum = 0.f, sq = 0.f;
#pragma unroll
  for (int j = 0; j < 8; ++j) { sum += xs[j]; sq += xs[j] * xs[j]; }
#pragma unroll
  for (int off = 1; off < 64; off <<= 1) {
    sum += __shfl_xor(sum, off, 64);
    sq += __shfl_xor(sq, off, 64);
  }
  float mean = sum * (1.f / 512.f);
  float var = sq * (1.f / 512.f) - mean * mean;
  float rs = rsqrtf(var + 1e-5f);
  short8 o;
#pragma unroll
  for (int j = 0; j < 8; ++j) {
    int c = lane * 8 + j;
    float val = (xs[j] - mean) * rs * (1.f + scv[c]) + shv[c];
    o[j] = f2bf(val);
  }
  *(short8*)(xout + (size_t)p * 512 + lane * 8) = o;
}

// ---------------------------------------------------------------------------
// K4: GEMM  C[M,N] = A[M,K](bf16) @ BT[N,K](bf16)^T + bias(f32), epilogues.
// 2-phase double-buffered m97 structure: 128x128 tile, BK=64,
// global_load_lds dwordx4 staging (G4 involution swizzle on source+read),
// stage(t+1) issued before compute(t), ONE vmcnt(0)+barrier per K-tile.
// 1-D grid, bn innermost (A-panel L2 reuse) + bijective chunked XCD swizzle.
// EPI: 0 = bias -> C bf16
//      1 = bias + tanh-GELU -> C bf16 (trunc pack)
//      2 = proj: scatter window-row -> token-row; Cf[s]=resid[s]+gate[col]*v (f32)
//      3 = fc2:  Cf[row]=resid[row]+gate[col]*v  (f32, Cf = d_out)
// ---------------------------------------------------------------------------
template <int EPI>
__global__ __launch_bounds__(256) void gemm_kernel(
    const short* __restrict__ A, const short* __restrict__ BT,
    const float* __restrict__ bias, void* __restrict__ Cv,
    int M, int N, int K, int nbn,
    const float* __restrict__ resid, const float* __restrict__ gate) {
  __shared__ __align__(16) short Atl[2][128 * 64];   // 2 x 16 KB
  __shared__ __align__(16) short Btl[2][128 * 64];   // 2 x 16 KB

  // bijective chunked XCD swizzle (m204), then bn-innermost decomposition
  int nwg = gridDim.x;
  int bid = blockIdx.x;
  int q = nwg >> 3, r = nwg & 7;
  int xcd = bid & 7, idx = bid >> 3;
  int swz = (xcd < r ? xcd * (q + 1) : r * (q + 1) + (xcd - r) * q) + idx;
  int bm = swz / nbn, bn = swz % nbn;

  int tid = threadIdx.x;
  int lane = tid & 63, wave = tid >> 6;
  int l15 = lane & 15, lg = lane >> 4;
  int wr = (wave >> 1) * 64, wc = (wave & 1) * 64;

  // staging address precompute: dest byte o (linear), src tile offset so = sigma(o)
  const size_t rowb = (size_t)K * 2;   // bytes per logical row
  const char* ga[4];
  const char* gb[4];
  int lo[4];
#pragma unroll
  for (int rr = 0; rr < 4; ++rr) {
    int o = rr * 4096 + tid * 16;
    int so = o ^ (((o >> 7) & 7) << 4);     // involution sigma
    int row = so >> 7, cb = so & 127;
    lo[rr] = o;
    ga[rr] = (const char*)A + (size_t)(bm * 128 + row) * rowb + cb;
    gb[rr] = (const char*)BT + (size_t)(bn * 128 + row) * rowb + cb;
  }

  f32x4 acc[4][4];
#pragma unroll
  for (int m = 0; m < 4; ++m)
#pragma unroll
    for (int n = 0; n < 4; ++n) acc[m][n] = (f32x4){0.f, 0.f, 0.f, 0.f};

  const int swr = (l15 & 7) << 4;

  auto stage = [&](int buf) {
#pragma unroll
    for (int rr = 0; rr < 4; ++rr) {
      __builtin_amdgcn_global_load_lds((gu32*)ga[rr], (lu32*)((char*)Atl[buf] + lo[rr]), 16, 0, 0);
      __builtin_amdgcn_global_load_lds((gu32*)gb[rr], (lu32*)((char*)Btl[buf] + lo[rr]), 16, 0, 0);
      ga[rr] += 128;  // advance 64 bf16 columns
      gb[rr] += 128;
    }
  };
  auto compute = [&](int buf) {
    short8 af[2][4], bfr[2][4];
#pragma unroll
    for (int m = 0; m < 4; ++m) {
      int base = (wr + m * 16 + l15) * 128;
#pragma unroll
      for (int ks = 0; ks < 2; ++ks)
        af[ks][m] = *(const short8*)((const char*)Atl[buf] + base + ((ks * 64 + lg * 16) ^ swr));
    }
#pragma unroll
    for (int n = 0; n < 4; ++n) {
      int base = (wc + n * 16 + l15) * 128;
#pragma unroll
      for (int ks = 0; ks < 2; ++ks)
        bfr[ks][n] = *(const short8*)((const char*)Btl[buf] + base + ((ks * 64 + lg * 16) ^ swr));
    }
#pragma unroll
    for (int ks = 0; ks < 2; ++ks)
#pragma unroll
      for (int m = 0; m < 4; ++m)
#pragma unroll
        for (int n = 0; n < 4; ++n)
          acc[m][n] = __builtin_amdgcn_mfma_f32_16x16x32_bf16(af[ks][m], bfr[ks][n], acc[m][n], 0, 0, 0);
  };

  const int nt = K >> 6;
  stage(0);
  __syncthreads();            // drain tile 0
  int cur = 0;
  for (int t = 0; t + 1 < nt; ++t) {
    stage(cur ^ 1);           // issue tile t+1 (flight hides under MFMA)
    compute(cur);
    __syncthreads();          // drain tile t+1 + all waves done reading buf cur
    cur ^= 1;
  }
  compute(cur);

#pragma unroll
  for (int m = 0; m < 4; ++m)
#pragma unroll
    for (int n = 0; n < 4; ++n) {
      int col = bn * 128 + wc + n * 16 + l15;
      float bv = bias[col];
#pragma unroll
      for (int i = 0; i < 4; ++i) {
        int row = bm * 128 + wr + m * 16 + lg * 4 + i;
        float v = acc[m][n][i] + bv;
        if (EPI == 0) {
          ((short*)Cv)[(size_t)row * N + col] = f2bf(v);
        } else if (EPI == 1) {
          // tanh-form GELU: v * sigmoid(2*sqrt(2/pi)*(v + 0.044715 v^3))
          float tt = v * (0.7978845608f + 0.0356774081f * v * v);
          float sg = 1.f / (1.f + __expf(-2.f * tt));
          ((short*)Cv)[(size_t)row * N + col] = f2bf_trunc(v * sg);
        } else if (EPI == 2) {
          int s = win_to_src(row);
          float xv = resid[(size_t)s * 512 + col];
          ((float*)Cv)[(size_t)s * 512 + col] = xv + gate[col] * v;
        } else {
          float xv = resid[(size_t)row * 512 + col];
          ((float*)Cv)[(size_t)row * 512 + col] = xv + gate[col] * v;
        }
      }
    }
}

// ---------------------------------------------------------------------------
// K5: window attention, one block per (window, head), 4 waves x 64 q-rows,
// flash-style online softmax over 4 key tiles of 64. qkv bf16 in ws.
// LDS 54272 B -> 3 blocks/CU. Bias via bf16 bs4 vector loads (biasT).
// P routed through per-wave LDS in 32-key slices (pl width 40).
// ---------------------------------------------------------------------------
__global__ __launch_bounds__(256) void attn_kernel(
    const short* __restrict__ qkv, const short* __restrict__ biasT,
    short* __restrict__ aout) {
  __shared__ __align__(16) short vt[64][264];      // V^T: [d][key]   33792 B
  __shared__ __align__(16) short pl[4][64][40];    // per-wave P slice 20480 B
  int win = blockIdx.x, head = blockIdx.y;
  int tid = threadIdx.x, lane = tid & 63, wave = tid >> 6;
  int l15 = lane & 15, lg = lane >> 4;
  const short* qp = qkv + (size_t)win * 256 * 1536 + head * 64;
  const short* kp = qp + 512;
  const short* vp = qp + 1024;

  // stage V transposed: v[key][d] -> vt[d][key]
#pragma unroll
  for (int r = 0; r < 8; ++r) {
    short8 vv = *(const short8*)(vp + (size_t)tid * 1536 + r * 8);
#pragma unroll
    for (int j = 0; j < 8; ++j) vt[r * 8 + j][tid] = vv[j];
  }

  // Q fragments (register-resident, reused across all key tiles)
  short8 qf[4][2];
#pragma unroll
  for (int m = 0; m < 4; ++m)
#pragma unroll
    for (int kk = 0; kk < 2; ++kk)
      qf[m][kk] = *(const short8*)(qp + (size_t)(wave * 64 + m * 16 + l15) * 1536 + kk * 32 + lg * 8);

  __syncthreads();

  float mrun[4][4], lrun[4][4];
  f32x4 ao[4][4];
#pragma unroll
  for (int m = 0; m < 4; ++m)
#pragma unroll
    for (int i = 0; i < 4; ++i) { mrun[m][i] = -1e30f; lrun[m][i] = 0.f; }
#pragma unroll
  for (int m = 0; m < 4; ++m)
#pragma unroll
    for (int n = 0; n < 4; ++n) ao[m][n] = (f32x4){0.f, 0.f, 0.f, 0.f};

  for (int kc = 0; kc < 4; ++kc) {
    // S = q @ k^T
    f32x4 sv[4][4];
#pragma unroll
    for (int m = 0; m < 4; ++m)
#pragma unroll
      for (int n = 0; n < 4; ++n) sv[m][n] = (f32x4){0.f, 0.f, 0.f, 0.f};
#pragma unroll
    for (int n = 0; n < 4; ++n)
#pragma unroll
      for (int kk = 0; kk < 2; ++kk) {
        short8 kf = *(const short8*)(kp + (size_t)(kc * 64 + n * 16 + l15) * 1536 + kk * 32 + lg * 8);
#pragma unroll
        for (int m = 0; m < 4; ++m)
          sv[m][n] = __builtin_amdgcn_mfma_f32_16x16x32_bf16(qf[m][kk], kf, sv[m][n], 0, 0, 0);
      }
    // scale + rel-pos bias: biasT[head][key][q], 4 consecutive q per lane
#pragma unroll
    for (int n = 0; n < 4; ++n) {
      const short* bq = biasT + (size_t)(head * 256 + kc * 64 + n * 16 + l15) * 256 + wave * 64 + lg * 4;
#pragma unroll
      for (int m = 0; m < 4; ++m) {
        bs4 bt = *(const bs4*)(bq + m * 16);
#pragma unroll
        for (int i = 0; i < 4; ++i)
          sv[m][n][i] = sv[m][n][i] * 0.125f + bf2f(bt[i]);
      }
    }
    // online softmax (row stats replicated across the 16 col-lanes)
#pragma unroll
    for (int m = 0; m < 4; ++m)
#pragma unroll
      for (int i = 0; i < 4; ++i) {
        float mx = fmaxf(fmaxf(sv[m][0][i], sv[m][1][i]), fmaxf(sv[m][2][i], sv[m][3][i]));
#pragma unroll
        for (int off = 1; off < 16; off <<= 1) mx = fmaxf(mx, __shfl_xor(mx, off, 64));
        float nm = fmaxf(mrun[m][i], mx);
        float corr = __expf(mrun[m][i] - nm);
        mrun[m][i] = nm;
        float rs = 0.f;
#pragma unroll
        for (int n = 0; n < 4; ++n) {
          float pe = __expf(sv[m][n][i] - nm);
          sv[m][n][i] = pe;
          rs += pe;
        }
#pragma unroll
        for (int off = 1; off < 16; off <<= 1) rs += __shfl_xor(rs, off, 64);
        lrun[m][i] = lrun[m][i] * corr + rs;
#pragma unroll
        for (int n = 0; n < 4; ++n) ao[m][n][i] *= corr;
      }
    // P slices of 32 keys: store -> read A-frag -> PV MFMA
#pragma unroll
    for (int s = 0; s < 2; ++s) {
#pragma unroll
      for (int m = 0; m < 4; ++m)
#pragma unroll
        for (int nn = 0; nn < 2; ++nn) {
          int n = 2 * s + nn;
#pragma unroll
          for (int i = 0; i < 4; ++i)
            pl[wave][m * 16 + lg * 4 + i][nn * 16 + l15] = f2bf_trunc(sv[m][n][i]);
        }
      short8 pf[4];
#pragma unroll
      for (int m = 0; m < 4; ++m)
        pf[m] = *(const short8*)&pl[wave][m * 16 + l15][lg * 8];
#pragma unroll
      for (int n2 = 0; n2 < 4; ++n2) {
        short8 vf = *(const short8*)&vt[n2 * 16 + l15][kc * 64 + s * 32 + lg * 8];
#pragma unroll
        for (int m = 0; m < 4; ++m)
          ao[m][n2] = __builtin_amdgcn_mfma_f32_16x16x32_bf16(pf[m], vf, ao[m][n2], 0, 0, 0);
      }
    }
  }

  // normalize + store [win-layout token][head*64+d]
#pragma unroll
  for (int m = 0; m < 4; ++m)
#pragma unroll
    for (int i = 0; i < 4; ++i) {
      float inv = 1.f / lrun[m][i];
      int row = win * 256 + wave * 64 + m * 16 + lg * 4 + i;
#pragma unroll
      for (int n = 0; n < 4; ++n)
        aout[(size_t)row * 512 + head * 64 + n * 16 + l15] = f2bf(ao[m][n][i] * inv);
    }
}

// ---------------------------------------------------------------------------
// launch
// ---------------------------------------------------------------------------
extern "C" void kernel_launch(void* const* d_in, const int* in_sizes, int n_in,
                              void* d_out, int out_size, void* d_ws, size_t ws_size,
                              hipStream_t stream) {
  (void)in_sizes; (void)n_in; (void)out_size; (void)ws_size;
  const float* x         = (const float*)d_in[0];
  const float* t_emb     = (const float*)d_in[1];
  const float* ada_w     = (const float*)d_in[2];
  const float* ada_b     = (const float*)d_in[3];
  const float* rel_table = (const float*)d_in[4];
  const float* qkv_w     = (const float*)d_in[5];
  const float* qkv_b     = (const float*)d_in[6];
  const float* proj_w    = (const float*)d_in[7];
  const float* proj_b    = (const float*)d_in[8];
  const float* fc1_w     = (const float*)d_in[9];
  const float* fc1_b     = (const float*)d_in[10];
  const float* fc2_w     = (const float*)d_in[11];
  const float* fc2_b     = (const float*)d_in[12];
  float* out = (float*)d_out;
  char* ws = (char*)d_ws;

  // workspace layout (bytes); total ~327 MB
  float* mod    = (float*)(ws);                    // 3072 f32 (16 KB reserved)
  short* biasT  = (short*)(ws + 16384);            // 8*256*256 bf16 = 1 MB
  short* qkvwT  = (short*)(ws + 16384 + 2097152);  // 1536*512 bf16
  short* projwT = qkvwT + 1536 * 512;              // 512*512
  short* fc1wT  = projwT + 512 * 512;              // 2048*512
  short* fc2wT  = fc1wT + 2048 * 512;              // 512*2048
  short* xn     = (short*)(ws + 8404992);          // 65536*512 bf16
  short* qkvb   = xn + (size_t)65536 * 512;        // 65536*1536 bf16
  short* attno  = qkvb + (size_t)65536 * 1536;     // 65536*512 bf16
  short* h1     = qkvb;                            // alias: 65536*2048 over qkvb+attno
  float* x2     = out;                             // MSA residual output lives in d_out

  mod_kernel<<<12, 256, 0, stream>>>(t_emb, ada_w, ada_b, mod);
  bias_kernel<<<2048, 256, 0, stream>>>(rel_table, biasT);
  transpose_kernel<<<dim3(48, 16), 256, 0, stream>>>(qkv_w, qkvwT, 512, 1536);
  transpose_kernel<<<dim3(16, 16), 256, 0, stream>>>(proj_w, projwT, 512, 512);
  transpose_kernel<<<dim3(64, 16), 256, 0, stream>>>(fc1_w, fc1wT, 512, 2048);
  transpose_kernel<<<dim3(16, 64), 256, 0, stream>>>(fc2_w, fc2wT, 2048, 512);

  // MSA: gather+LN+modulate -> xn (window layout, bf16)
  ln_kernel<1><<<16384, 256, 0, stream>>>(x, xn, mod + 0, mod + 512);
  // qkv = xn @ qkv_w + b  (bf16); N=1536 -> nbn=12
  gemm_kernel<0><<<512 * 12, 256, 0, stream>>>(xn, qkvwT, qkv_b, qkvb,
                                               65536, 1536, 512, 12, nullptr, nullptr);
  attn_kernel<<<dim3(256, 8), 256, 0, stream>>>(qkvb, biasT, attno);
  // proj + scatter-back + gated residual -> x2 (token layout, f32 in d_out)
  gemm_kernel<2><<<512 * 4, 256, 0, stream>>>(attno, projwT, proj_b, x2,
                                              65536, 512, 512, 4, x, mod + 1024);
  // MLP: LN+modulate -> xn (bf16)
  ln_kernel<0><<<16384, 256, 0, stream>>>(x2, xn, mod + 1536, mod + 2048);
  gemm_kernel<1><<<512 * 16, 256, 0, stream>>>(xn, fc1wT, fc1_b, h1,
                                               65536, 2048, 512, 16, nullptr, nullptr);
  gemm_kernel<3><<<512 * 4, 256, 0, stream>>>(h1, fc2wT, fc2_b, out,
                                              65536, 512, 2048, 4, x2, mod + 2560);
}

// Round 7
// 898.434 us; speedup vs baseline: 1.1942x; 1.1942x over previous
//
#include <hip/hip_runtime.h>
#include <hip/hip_bf16.h>
#include <math.h>

// ---------------------------------------------------------------------------
// SwinDiT block, f32 I/O + bf16 MFMA internals, MI355X.
// B=1, D=16,H=64,W=64 -> L=65536 tokens, C=512. Windows 4x8x8=256 tokens,
// 256 windows, 8 heads, d=64. HIDDEN=2048.
// ---------------------------------------------------------------------------

typedef __attribute__((ext_vector_type(8))) short short8;   // 8 x bf16
typedef __attribute__((ext_vector_type(4))) short bs4;      // 4 x bf16
typedef __attribute__((ext_vector_type(4))) float f32x4;

typedef const __attribute__((address_space(1))) unsigned int gu32;
typedef __attribute__((address_space(3))) unsigned int lu32;

__device__ __forceinline__ float bf2f(short s) {
  unsigned int u = ((unsigned int)(unsigned short)s) << 16;
  float f;
  __builtin_memcpy(&f, &u, 4);
  return f;
}
__device__ __forceinline__ short f2bf(float f) {
  unsigned int u;
  __builtin_memcpy(&u, &f, 4);
  u += 0x7FFFu + ((u >> 16) & 1u);   // RNE
  return (short)(u >> 16);
}
__device__ __forceinline__ short f2bf_trunc(float f) {
  unsigned int u;
  __builtin_memcpy(&u, &f, 4);
  return (short)(u >> 16);
}

// window-layout row p -> original token index s (roll(-2,-4,-4) + window partition)
__device__ __forceinline__ int win_to_src(int p) {
  int wi = p >> 8, t = p & 255;
  int sd = (((wi >> 6) << 2) + (t >> 6) + 2) & 15;
  int sh = ((((wi >> 3) & 7) << 3) + ((t >> 3) & 7) + 4) & 63;
  int sw = (((wi & 7) << 3) + (t & 7) + 4) & 63;
  return (sd << 12) | (sh << 6) | sw;
}

// ---------------------------------------------------------------------------
// K0: mod = silu(t_emb) @ ada_w + ada_b   -> f32 [3072]
// ---------------------------------------------------------------------------
__global__ __launch_bounds__(256) void mod_kernel(
    const float* __restrict__ t_emb, const float* __restrict__ ada_w,
    const float* __restrict__ ada_b, float* __restrict__ mod) {
  __shared__ float sl[512];
  int tid = threadIdx.x;
  for (int r = 0; r < 2; ++r) {
    float x = t_emb[r * 256 + tid];
    sl[r * 256 + tid] = x / (1.f + expf(-x));
  }
  __syncthreads();
  int col = blockIdx.x * 256 + tid;
  float acc = ada_b[col];
  for (int k = 0; k < 512; ++k)
    acc += sl[k] * ada_w[(size_t)k * 3072 + col];
  mod[col] = acc;
}

// ---------------------------------------------------------------------------
// K1: rel-pos bias expand, TRANSPOSED bf16: biasT[head][key j][q i]
// ---------------------------------------------------------------------------
__global__ __launch_bounds__(256) void bias_kernel(
    const float* __restrict__ rel_table, short* __restrict__ biasT) {
  int head = blockIdx.x >> 8;
  int j = blockIdx.x & 255;   // key
  int i = threadIdx.x;        // q
  int di = i >> 6, hi = (i >> 3) & 7, wi = i & 7;
  int dj = j >> 6, hj = (j >> 3) & 7, wj = j & 7;
  int idx = (di - dj + 3) * 225 + (hi - hj + 7) * 15 + (wi - wj + 7);
  biasT[(size_t)blockIdx.x * 256 + i] = f2bf(rel_table[idx * 8 + head]);
}

// ---------------------------------------------------------------------------
// K2: transpose + convert: f32 [K,N] -> bf16 [N,K]
// ---------------------------------------------------------------------------
__global__ __launch_bounds__(256) void transpose_kernel(
    const float* __restrict__ in, short* __restrict__ out, int K, int N) {
  __shared__ short t[32][33];
  int n0 = blockIdx.x * 32, k0 = blockIdx.y * 32;
  int tx = threadIdx.x & 31, ty = threadIdx.x >> 5;
#pragma unroll
  for (int r = 0; r < 4; ++r)
    t[ty + r * 8][tx] = f2bf(in[(size_t)(k0 + ty + r * 8) * N + n0 + tx]);
  __syncthreads();
#pragma unroll
  for (int r = 0; r < 4; ++r)
    out[(size_t)(n0 + ty + r * 8) * K + k0 + tx] = t[tx][ty + r * 8];
}

// ---------------------------------------------------------------------------
// K3: LayerNorm + adaLN modulate. f32 in -> bf16 out.
// GATHER=1: out row p <- src row win_to_src(p)
// ---------------------------------------------------------------------------
template <int GATHER>
__global__ __launch_bounds__(256) void ln_kernel(
    const float* __restrict__ xin, short* __restrict__ xout,
    const float* __restrict__ shv, const float* __restrict__ scv) {
  int wave = threadIdx.x >> 6, lane = threadIdx.x & 63;
  int p = blockIdx.x * 4 + wave;
  int s = GATHER ? win_to_src(p) : p;
  const f32x4* px = (const f32x4*)(xin + (size_t)s * 512 + lane * 8);
  f32x4 a = px[0], b = px[1];
  float xs[8];
#pragma unroll
  for (int j = 0; j < 4; ++j) { xs[j] = a[j]; xs[4 + j] = b[j]; }
  float sum = 0.f, sq = 0.f;
#pragma unroll
  for (int j = 0; j < 8; ++j) { sum += xs[j]; sq += xs[j] * xs[j]; }
#pragma unroll
  for (int off = 1; off < 64; off <<= 1) {
    sum += __shfl_xor(sum, off, 64);
    sq += __shfl_xor(sq, off, 64);
  }
  float mean = sum * (1.f / 512.f);
  float var = sq * (1.f / 512.f) - mean * mean;
  float rs = rsqrtf(var + 1e-5f);
  short8 o;
#pragma unroll
  for (int j = 0; j < 8; ++j) {
    int c = lane * 8 + j;
    float val = (xs[j] - mean) * rs * (1.f + scv[c]) + shv[c];
    o[j] = f2bf(val);
  }
  *(short8*)(xout + (size_t)p * 512 + lane * 8) = o;
}

// ---------------------------------------------------------------------------
// K4: GEMM  C[M,N] = A[M,K](bf16) @ BT[N,K](bf16)^T + bias(f32), epilogues.
// 256x128 tile, BK=64, 8 waves (512 thr), each wave a 64x64 sub-tile (4x4
// frags of 16x16x32). Single-buffer 2-barrier loop (m97 schedule),
// global_load_lds dwordx4 with G4 involution swizzle on source+read.
// LDS 48 KB -> 3 blocks/CU. 1-D grid, bn innermost + bijective XCD chunking.
// EPI: 0 = bias -> C bf16
//      1 = bias + tanh-GELU -> C bf16 (trunc pack)
//      2 = proj: scatter window-row -> token-row; Cf[s]=resid[s]+gate[col]*v (f32)
//      3 = fc2:  Cf[row]=resid[row]+gate[col]*v  (f32, Cf = d_out)
// ---------------------------------------------------------------------------
template <int EPI>
__global__ __launch_bounds__(512) void gemm_kernel(
    const short* __restrict__ A, const short* __restrict__ BT,
    const float* __restrict__ bias, void* __restrict__ Cv,
    int M, int N, int K, int nbn,
    const float* __restrict__ resid, const float* __restrict__ gate) {
  __shared__ __align__(16) short Atl[256 * 64];   // 32 KB
  __shared__ __align__(16) short Btl[128 * 64];   // 16 KB

  // bijective chunked XCD swizzle (m204), then bn-innermost decomposition
  int nwg = gridDim.x;
  int bid = blockIdx.x;
  int q = nwg >> 3, r = nwg & 7;
  int xcd = bid & 7, idx = bid >> 3;
  int swz = (xcd < r ? xcd * (q + 1) : r * (q + 1) + (xcd - r) * q) + idx;
  int bm = swz / nbn, bn = swz % nbn;

  int tid = threadIdx.x;
  int lane = tid & 63, wave = tid >> 6;          // wave 0..7
  int l15 = lane & 15, lg = lane >> 4;
  int wr = (wave >> 1) * 64, wc = (wave & 1) * 64;   // 4x2 wave grid

  // staging address precompute: dest byte o (linear), src tile offset so = sigma(o)
  const size_t rowb = (size_t)K * 2;   // bytes per logical row
  const char* ga[4];
  const char* gb[2];
  int loA[4], loB[2];
#pragma unroll
  for (int rr = 0; rr < 4; ++rr) {
    int o = rr * 8192 + tid * 16;
    int so = o ^ (((o >> 7) & 7) << 4);     // involution sigma
    int row = so >> 7, cb = so & 127;
    loA[rr] = o;
    ga[rr] = (const char*)A + (size_t)(bm * 256 + row) * rowb + cb;
  }
#pragma unroll
  for (int rr = 0; rr < 2; ++rr) {
    int o = rr * 8192 + tid * 16;
    int so = o ^ (((o >> 7) & 7) << 4);
    int row = so >> 7, cb = so & 127;
    loB[rr] = o;
    gb[rr] = (const char*)BT + (size_t)(bn * 128 + row) * rowb + cb;
  }

  f32x4 acc[4][4];
#pragma unroll
  for (int m = 0; m < 4; ++m)
#pragma unroll
    for (int n = 0; n < 4; ++n) acc[m][n] = (f32x4){0.f, 0.f, 0.f, 0.f};

  const int swr = (l15 & 7) << 4;

  for (int kt = 0; kt < K; kt += 64) {
#pragma unroll
    for (int rr = 0; rr < 4; ++rr) {
      __builtin_amdgcn_global_load_lds((gu32*)ga[rr], (lu32*)((char*)Atl + loA[rr]), 16, 0, 0);
      ga[rr] += 128;
    }
#pragma unroll
    for (int rr = 0; rr < 2; ++rr) {
      __builtin_amdgcn_global_load_lds((gu32*)gb[rr], (lu32*)((char*)Btl + loB[rr]), 16, 0, 0);
      gb[rr] += 128;
    }
    __syncthreads();

    short8 af[2][4], bfr[2][4];
#pragma unroll
    for (int m = 0; m < 4; ++m) {
      int base = (wr + m * 16 + l15) * 128;
#pragma unroll
      for (int ks = 0; ks < 2; ++ks)
        af[ks][m] = *(const short8*)((const char*)Atl + base + ((ks * 64 + lg * 16) ^ swr));
    }
#pragma unroll
    for (int n = 0; n < 4; ++n) {
      int base = (wc + n * 16 + l15) * 128;
#pragma unroll
      for (int ks = 0; ks < 2; ++ks)
        bfr[ks][n] = *(const short8*)((const char*)Btl + base + ((ks * 64 + lg * 16) ^ swr));
    }
#pragma unroll
    for (int ks = 0; ks < 2; ++ks)
#pragma unroll
      for (int m = 0; m < 4; ++m)
#pragma unroll
        for (int n = 0; n < 4; ++n)
          acc[m][n] = __builtin_amdgcn_mfma_f32_16x16x32_bf16(af[ks][m], bfr[ks][n], acc[m][n], 0, 0, 0);
    __syncthreads();
  }

#pragma unroll
  for (int m = 0; m < 4; ++m)
#pragma unroll
    for (int n = 0; n < 4; ++n) {
      int col = bn * 128 + wc + n * 16 + l15;
      float bv = bias[col];
#pragma unroll
      for (int i = 0; i < 4; ++i) {
        int row = bm * 256 + wr + m * 16 + lg * 4 + i;
        float v = acc[m][n][i] + bv;
        if (EPI == 0) {
          ((short*)Cv)[(size_t)row * N + col] = f2bf_trunc(v);
        } else if (EPI == 1) {
          // tanh-form GELU: v * sigmoid(2*sqrt(2/pi)*(v + 0.044715 v^3))
          float tt = v * (0.7978845608f + 0.0356774081f * v * v);
          float sg = 1.f / (1.f + __expf(-2.f * tt));
          ((short*)Cv)[(size_t)row * N + col] = f2bf_trunc(v * sg);
        } else if (EPI == 2) {
          int s = win_to_src(row);
          float xv = resid[(size_t)s * 512 + col];
          ((float*)Cv)[(size_t)s * 512 + col] = xv + gate[col] * v;
        } else {
          float xv = resid[(size_t)row * 512 + col];
          ((float*)Cv)[(size_t)row * 512 + col] = xv + gate[col] * v;
        }
      }
    }
}

// ---------------------------------------------------------------------------
// K5: window attention, one block per (window, head), 4 waves x 64 q-rows,
// flash-style online softmax over 4 key tiles of 64. qkv bf16 in ws.
// LDS 54272 B -> 3 blocks/CU. Bias via bf16 bs4 vector loads (biasT).
// Q pre-scaled by 0.125 (exact exponent shift). P via per-wave LDS slices.
// ---------------------------------------------------------------------------
__global__ __launch_bounds__(256) void attn_kernel(
    const short* __restrict__ qkv, const short* __restrict__ biasT,
    short* __restrict__ aout) {
  __shared__ __align__(16) short vt[64][264];      // V^T: [d][key]   33792 B
  __shared__ __align__(16) short pl[4][64][40];    // per-wave P slice 20480 B
  int win = blockIdx.x, head = blockIdx.y;
  int tid = threadIdx.x, lane = tid & 63, wave = tid >> 6;
  int l15 = lane & 15, lg = lane >> 4;
  const short* qp = qkv + (size_t)win * 256 * 1536 + head * 64;
  const short* kp = qp + 512;
  const short* vp = qp + 1024;

  // stage V transposed: v[key][d] -> vt[d][key]
#pragma unroll
  for (int r = 0; r < 8; ++r) {
    short8 vv = *(const short8*)(vp + (size_t)tid * 1536 + r * 8);
#pragma unroll
    for (int j = 0; j < 8; ++j) vt[r * 8 + j][tid] = vv[j];
  }

  // Q fragments, pre-scaled by 0.125 (exact for bf16: exponent -3)
  short8 qf[4][2];
#pragma unroll
  for (int m = 0; m < 4; ++m)
#pragma unroll
    for (int kk = 0; kk < 2; ++kk) {
      short8 v = *(const short8*)(qp + (size_t)(wave * 64 + m * 16 + l15) * 1536 + kk * 32 + lg * 8);
#pragma unroll
      for (int j = 0; j < 8; ++j) v[j] = f2bf_trunc(bf2f(v[j]) * 0.125f);
      qf[m][kk] = v;
    }

  __syncthreads();

  float mrun[4][4], lrun[4][4];
  f32x4 ao[4][4];
#pragma unroll
  for (int m = 0; m < 4; ++m)
#pragma unroll
    for (int i = 0; i < 4; ++i) { mrun[m][i] = -1e30f; lrun[m][i] = 0.f; }
#pragma unroll
  for (int m = 0; m < 4; ++m)
#pragma unroll
    for (int n = 0; n < 4; ++n) ao[m][n] = (f32x4){0.f, 0.f, 0.f, 0.f};

  for (int kc = 0; kc < 4; ++kc) {
    // S = (q*scale) @ k^T
    f32x4 sv[4][4];
#pragma unroll
    for (int m = 0; m < 4; ++m)
#pragma unroll
      for (int n = 0; n < 4; ++n) sv[m][n] = (f32x4){0.f, 0.f, 0.f, 0.f};
#pragma unroll
    for (int n = 0; n < 4; ++n)
#pragma unroll
      for (int kk = 0; kk < 2; ++kk) {
        short8 kf = *(const short8*)(kp + (size_t)(kc * 64 + n * 16 + l15) * 1536 + kk * 32 + lg * 8);
#pragma unroll
        for (int m = 0; m < 4; ++m)
          sv[m][n] = __builtin_amdgcn_mfma_f32_16x16x32_bf16(qf[m][kk], kf, sv[m][n], 0, 0, 0);
      }
    // rel-pos bias: biasT[head][key][q], 4 consecutive q per lane
#pragma unroll
    for (int n = 0; n < 4; ++n) {
      const short* bq = biasT + (size_t)(head * 256 + kc * 64 + n * 16 + l15) * 256 + wave * 64 + lg * 4;
#pragma unroll
      for (int m = 0; m < 4; ++m) {
        bs4 bt = *(const bs4*)(bq + m * 16);
#pragma unroll
        for (int i = 0; i < 4; ++i)
          sv[m][n][i] = sv[m][n][i] + bf2f(bt[i]);
      }
    }
    // online softmax (row stats replicated across the 16 col-lanes)
#pragma unroll
    for (int m = 0; m < 4; ++m)
#pragma unroll
      for (int i = 0; i < 4; ++i) {
        float mx = fmaxf(fmaxf(sv[m][0][i], sv[m][1][i]), fmaxf(sv[m][2][i], sv[m][3][i]));
#pragma unroll
        for (int off = 1; off < 16; off <<= 1) mx = fmaxf(mx, __shfl_xor(mx, off, 64));
        float nm = fmaxf(mrun[m][i], mx);
        float corr = __expf(mrun[m][i] - nm);
        mrun[m][i] = nm;
        float rs = 0.f;
#pragma unroll
        for (int n = 0; n < 4; ++n) {
          float pe = __expf(sv[m][n][i] - nm);
          sv[m][n][i] = pe;
          rs += pe;
        }
#pragma unroll
        for (int off = 1; off < 16; off <<= 1) rs += __shfl_xor(rs, off, 64);
        lrun[m][i] = lrun[m][i] * corr + rs;
#pragma unroll
        for (int n = 0; n < 4; ++n) ao[m][n][i] *= corr;
      }
    // P slices of 32 keys: store -> read A-frag -> PV MFMA
#pragma unroll
    for (int s = 0; s < 2; ++s) {
#pragma unroll
      for (int m = 0; m < 4; ++m)
#pragma unroll
        for (int nn = 0; nn < 2; ++nn) {
          int n = 2 * s + nn;
#pragma unroll
          for (int i = 0; i < 4; ++i)
            pl[wave][m * 16 + lg * 4 + i][nn * 16 + l15] = f2bf_trunc(sv[m][n][i]);
        }
      short8 pf[4];
#pragma unroll
      for (int m = 0; m < 4; ++m)
        pf[m] = *(const short8*)&pl[wave][m * 16 + l15][lg * 8];
#pragma unroll
      for (int n2 = 0; n2 < 4; ++n2) {
        short8 vf = *(const short8*)&vt[n2 * 16 + l15][kc * 64 + s * 32 + lg * 8];
#pragma unroll
        for (int m = 0; m < 4; ++m)
          ao[m][n2] = __builtin_amdgcn_mfma_f32_16x16x32_bf16(pf[m], vf, ao[m][n2], 0, 0, 0);
      }
    }
  }

  // normalize + store [win-layout token][head*64+d]
#pragma unroll
  for (int m = 0; m < 4; ++m)
#pragma unroll
    for (int i = 0; i < 4; ++i) {
      float inv = 1.f / lrun[m][i];
      int row = win * 256 + wave * 64 + m * 16 + lg * 4 + i;
#pragma unroll
      for (int n = 0; n < 4; ++n)
        aout[(size_t)row * 512 + head * 64 + n * 16 + l15] = f2bf(ao[m][n][i] * inv);
    }
}

// ---------------------------------------------------------------------------
// launch
// ---------------------------------------------------------------------------
extern "C" void kernel_launch(void* const* d_in, const int* in_sizes, int n_in,
                              void* d_out, int out_size, void* d_ws, size_t ws_size,
                              hipStream_t stream) {
  (void)in_sizes; (void)n_in; (void)out_size; (void)ws_size;
  const float* x         = (const float*)d_in[0];
  const float* t_emb     = (const float*)d_in[1];
  const float* ada_w     = (const float*)d_in[2];
  const float* ada_b     = (const float*)d_in[3];
  const float* rel_table = (const float*)d_in[4];
  const float* qkv_w     = (const float*)d_in[5];
  const float* qkv_b     = (const float*)d_in[6];
  const float* proj_w    = (const float*)d_in[7];
  const float* proj_b    = (const float*)d_in[8];
  const float* fc1_w     = (const float*)d_in[9];
  const float* fc1_b     = (const float*)d_in[10];
  const float* fc2_w     = (const float*)d_in[11];
  const float* fc2_b     = (const float*)d_in[12];
  float* out = (float*)d_out;
  char* ws = (char*)d_ws;

  // workspace layout (bytes); total ~327 MB
  float* mod    = (float*)(ws);                    // 3072 f32 (16 KB reserved)
  short* biasT  = (short*)(ws + 16384);            // 8*256*256 bf16 = 1 MB
  short* qkvwT  = (short*)(ws + 16384 + 2097152);  // 1536*512 bf16
  short* projwT = qkvwT + 1536 * 512;              // 512*512
  short* fc1wT  = projwT + 512 * 512;              // 2048*512
  short* fc2wT  = fc1wT + 2048 * 512;              // 512*2048
  short* xn     = (short*)(ws + 8404992);          // 65536*512 bf16
  short* qkvb   = xn + (size_t)65536 * 512;        // 65536*1536 bf16
  short* attno  = qkvb + (size_t)65536 * 1536;     // 65536*512 bf16
  short* h1     = qkvb;                            // alias: 65536*2048 over qkvb+attno
  float* x2     = out;                             // MSA residual output lives in d_out

  mod_kernel<<<12, 256, 0, stream>>>(t_emb, ada_w, ada_b, mod);
  bias_kernel<<<2048, 256, 0, stream>>>(rel_table, biasT);
  transpose_kernel<<<dim3(48, 16), 256, 0, stream>>>(qkv_w, qkvwT, 512, 1536);
  transpose_kernel<<<dim3(16, 16), 256, 0, stream>>>(proj_w, projwT, 512, 512);
  transpose_kernel<<<dim3(64, 16), 256, 0, stream>>>(fc1_w, fc1wT, 512, 2048);
  transpose_kernel<<<dim3(16, 64), 256, 0, stream>>>(fc2_w, fc2wT, 2048, 512);

  // MSA: gather+LN+modulate -> xn (window layout, bf16)
  ln_kernel<1><<<16384, 256, 0, stream>>>(x, xn, mod + 0, mod + 512);
  // qkv = xn @ qkv_w + b  (bf16); BM=256,BN=128 -> grid 256*12
  gemm_kernel<0><<<256 * 12, 512, 0, stream>>>(xn, qkvwT, qkv_b, qkvb,
                                               65536, 1536, 512, 12, nullptr, nullptr);
  attn_kernel<<<dim3(256, 8), 256, 0, stream>>>(qkvb, biasT, attno);
  // proj + scatter-back + gated residual -> x2 (token layout, f32 in d_out)
  gemm_kernel<2><<<256 * 4, 512, 0, stream>>>(attno, projwT, proj_b, x2,
                                              65536, 512, 512, 4, x, mod + 1024);
  // MLP: LN+modulate -> xn (bf16)
  ln_kernel<0><<<16384, 256, 0, stream>>>(x2, xn, mod + 1536, mod + 2048);
  gemm_kernel<1><<<256 * 16, 512, 0, stream>>>(xn, fc1wT, fc1_b, h1,
                                               65536, 2048, 512, 16, nullptr, nullptr);
  gemm_kernel<3><<<256 * 4, 512, 0, stream>>>(h1, fc2wT, fc2_b, out,
                                              65536, 512, 2048, 4, x2, mod + 2560);
}